// Round 2
// baseline (119.938 us; speedup 1.0000x reference)
//
#include <hip/hip_runtime.h>
#include <hip/hip_bf16.h>

// Problem constants
#define HEIGHT 480
#define WIDTH  640
#define IN_CH  6
#define CIN    8      // p, 1-p, 6 features
#define COUT   32
#define BATCH  8
#define NPTS   16384
#define NPTOT  (BATCH * NPTS)          // 131072 = 2^17
// Padded grid: rows 0..482 (point rows 1..481), cols 0..642 (point cols 1..641)
#define GH 483
#define GW 643

// grid layout: [b][gy][gx][cin], cin contiguous (32B per cell, aligned)
__device__ __forceinline__ size_t cell_off(int b, int gy, int gx) {
    return ((((size_t)b * GH + gy) * GW + gx) << 3);
}

// One thread per (channel, point): idx = c*2^17 + point.
// A wave's 64 lanes = 64 consecutive points, same channel -> 64 distinct
// random cache lines (no intra-wave same-line atomic serialization), and
// coalesced xytp float4 reads.
__global__ void scatter_kernel(const float4* __restrict__ xytp,
                               const float*  __restrict__ feats,
                               float* __restrict__ grid) {
    int idx = blockIdx.x * blockDim.x + threadIdx.x;
    if (idx >= NPTOT * CIN) return;
    int c     = idx >> 17;
    int point = idx & (NPTOT - 1);
    float4 q = xytp[point];               // (t, x, y, p)
    int gy = (int)rintf(q.z * (float)HEIGHT) + 1;   // padded coord
    int gx = (int)rintf(q.y * (float)WIDTH) + 1;
    int b  = point >> 14;                 // NPTS = 16384
    float v;
    if (c == 0)      v = q.w;
    else if (c == 1) v = 1.0f - q.w;
    else             v = feats[(size_t)point * IN_CH + (c - 2)];
    atomicAdd(grid + cell_off(b, gy, gx) + c, v);
}

// Two threads per point; each computes 16 of the 32 output channels.
__global__ void conv_gather_kernel(const float4* __restrict__ xytp,
                                   const float*  __restrict__ grid,
                                   const float*  __restrict__ W,     // [3][3][8][32]
                                   const float*  __restrict__ bias,  // [32]
                                   float* __restrict__ out) {
    int idx = blockIdx.x * blockDim.x + threadIdx.x;
    if (idx >= NPTOT * 2) return;
    int point = idx >> 1;
    int half  = idx & 1;
    int cbase = half * 16;

    float4 q = xytp[point];
    int gy = (int)rintf(q.z * (float)HEIGHT);   // window = padded rows gy..gy+2
    int gx = (int)rintf(q.y * (float)WIDTH);
    int b  = point >> 14;

    float acc[16];
#pragma unroll
    for (int c = 0; c < 16; ++c) acc[c] = bias[cbase + c];

    const float* gbase = grid + cell_off(b, gy, gx);

#pragma unroll
    for (int ky = 0; ky < 3; ++ky) {
#pragma unroll
        for (int kx = 0; kx < 3; ++kx) {
            const float* cell = gbase + ((size_t)(ky * GW + kx) << 3);
            float4 g0 = *(const float4*)(cell);
            float4 g1 = *(const float4*)(cell + 4);
            float g[CIN] = {g0.x, g0.y, g0.z, g0.w, g1.x, g1.y, g1.z, g1.w};
            const float* wp = W + (ky * 3 + kx) * CIN * COUT + cbase;
#pragma unroll
            for (int ci = 0; ci < CIN; ++ci) {
#pragma unroll
                for (int c = 0; c < 16; ++c) {
                    acc[c] = fmaf(g[ci], wp[ci * COUT + c], acc[c]);
                }
            }
        }
    }

    float* o = out + (size_t)point * COUT + cbase;
#pragma unroll
    for (int c = 0; c < 16; c += 4) {
        *(float4*)(o + c) = make_float4(acc[c], acc[c + 1], acc[c + 2], acc[c + 3]);
    }
}

extern "C" void kernel_launch(void* const* d_in, const int* in_sizes, int n_in,
                              void* d_out, int out_size, void* d_ws, size_t ws_size,
                              hipStream_t stream) {
    const float4* xytp  = (const float4*)d_in[0];   // (8,16384,4)
    const float*  feats = (const float*)d_in[1];    // (8,16384,6)
    const float*  W     = (const float*)d_in[2];    // (3,3,8,32)
    const float*  bias  = (const float*)d_in[3];    // (32,)
    float* out = (float*)d_out;                     // (8,16384,32)

    float* grid = (float*)d_ws;
    const size_t grid_bytes = (size_t)BATCH * GH * GW * CIN * sizeof(float); // ~79.5 MB

    hipMemsetAsync(grid, 0, grid_bytes, stream);

    const int blk = 256;

    const int n_scatter = NPTOT * CIN;   // 1,048,576 threads, 1 atomic each
    scatter_kernel<<<(n_scatter + blk - 1) / blk, blk, 0, stream>>>(xytp, feats, grid);

    const int n_conv = NPTOT * 2;        // 262,144 threads, 16 couts each
    conv_gather_kernel<<<(n_conv + blk - 1) / blk, blk, 0, stream>>>(xytp, grid, W, bias, out);
}

// Round 3
// 103.636 us; speedup vs baseline: 1.1573x; 1.1573x over previous
//
#include <hip/hip_runtime.h>
#include <hip/hip_bf16.h>

// Problem constants
#define HEIGHT 480
#define WIDTH  640
#define IN_CH  6
#define CIN    8      // p, 1-p, 6 features
#define COUT   32
#define BATCH  8
#define NPTS   16384
#define NPTOT  (BATCH * NPTS)          // 131072 = 2^17
// Padded grid: rows 0..482 (point rows 1..481), cols 0..642 (point cols 1..641)
#define GH 483
#define GW 643

// grid layout: [b][gy][gx][cin], cin contiguous (32B per cell, aligned)
__device__ __forceinline__ size_t cell_off(int b, int gy, int gx) {
    return ((((size_t)b * GH + gy) * GW + gx) << 3);
}

// One thread per (channel, point): idx = c*2^17 + point.
// A wave's 64 lanes = 64 consecutive points, same channel -> 64 distinct
// random cache lines, coalesced xytp float4 reads.
// unsafeAtomicAdd -> HW global_atomic_add_f32 (no CAS loop).
__global__ void scatter_kernel(const float4* __restrict__ xytp,
                               const float*  __restrict__ feats,
                               float* __restrict__ grid) {
    int idx = blockIdx.x * blockDim.x + threadIdx.x;
    if (idx >= NPTOT * CIN) return;
    int c     = idx >> 17;
    int point = idx & (NPTOT - 1);
    float4 q = xytp[point];               // (t, x, y, p)
    int gy = (int)rintf(q.z * (float)HEIGHT) + 1;   // padded coord
    int gx = (int)rintf(q.y * (float)WIDTH) + 1;
    int b  = point >> 14;                 // NPTS = 16384
    float v;
    if (c == 0)      v = q.w;
    else if (c == 1) v = 1.0f - q.w;
    else             v = feats[(size_t)point * IN_CH + (c - 2)];
    unsafeAtomicAdd(grid + cell_off(b, gy, gx) + c, v);
}

// One thread per point, all 32 output channels.
__global__ void conv_gather_kernel(const float4* __restrict__ xytp,
                                   const float*  __restrict__ grid,
                                   const float*  __restrict__ W,     // [3][3][8][32]
                                   const float*  __restrict__ bias,  // [32]
                                   float* __restrict__ out) {
    int idx = blockIdx.x * blockDim.x + threadIdx.x;
    if (idx >= NPTOT) return;
    float4 q = xytp[idx];
    int gy = (int)rintf(q.z * (float)HEIGHT);   // window = padded rows gy..gy+2
    int gx = (int)rintf(q.y * (float)WIDTH);
    int b  = idx >> 14;

    float acc[COUT];
#pragma unroll
    for (int c = 0; c < COUT; ++c) acc[c] = bias[c];

    const float* gbase = grid + cell_off(b, gy, gx);

#pragma unroll
    for (int ky = 0; ky < 3; ++ky) {
#pragma unroll
        for (int kx = 0; kx < 3; ++kx) {
            const float* cell = gbase + ((size_t)(ky * GW + kx) << 3);
            float4 g0 = *(const float4*)(cell);
            float4 g1 = *(const float4*)(cell + 4);
            float g[CIN] = {g0.x, g0.y, g0.z, g0.w, g1.x, g1.y, g1.z, g1.w};
            const float* wp = W + (ky * 3 + kx) * CIN * COUT;
#pragma unroll
            for (int ci = 0; ci < CIN; ++ci) {
#pragma unroll
                for (int c = 0; c < COUT; ++c) {
                    acc[c] = fmaf(g[ci], wp[ci * COUT + c], acc[c]);
                }
            }
        }
    }

    float* o = out + (size_t)idx * COUT;
#pragma unroll
    for (int c = 0; c < COUT; c += 4) {
        *(float4*)(o + c) = make_float4(acc[c], acc[c + 1], acc[c + 2], acc[c + 3]);
    }
}

extern "C" void kernel_launch(void* const* d_in, const int* in_sizes, int n_in,
                              void* d_out, int out_size, void* d_ws, size_t ws_size,
                              hipStream_t stream) {
    const float4* xytp  = (const float4*)d_in[0];   // (8,16384,4)
    const float*  feats = (const float*)d_in[1];    // (8,16384,6)
    const float*  W     = (const float*)d_in[2];    // (3,3,8,32)
    const float*  bias  = (const float*)d_in[3];    // (32,)
    float* out = (float*)d_out;                     // (8,16384,32)

    float* grid = (float*)d_ws;
    const size_t grid_bytes = (size_t)BATCH * GH * GW * CIN * sizeof(float); // ~79.5 MB

    hipMemsetAsync(grid, 0, grid_bytes, stream);

    const int blk = 256;

    const int n_scatter = NPTOT * CIN;   // 1,048,576 threads, 1 HW atomic each
    scatter_kernel<<<(n_scatter + blk - 1) / blk, blk, 0, stream>>>(xytp, feats, grid);

    conv_gather_kernel<<<(NPTOT + blk - 1) / blk, blk, 0, stream>>>(xytp, grid, W, bias, out);
}

// Round 4
// 64.762 us; speedup vs baseline: 1.8520x; 1.6003x over previous
//
#include <hip/hip_runtime.h>
#include <hip/hip_bf16.h>

// Problem constants
#define HEIGHT 480
#define WIDTH  640
#define IN_CH  6
#define CIN    8      // p, 1-p, 6 features
#define COUT   32
#define BATCH  8
#define NPTS   16384
#define NPTOT  (BATCH * NPTS)          // 131072 = 2^17
// Padded grid: rows 0..482 (point rows 1..481), cols 0..642 (point cols 1..641)
#define GH 483
#define GW 643
#define NCELLS ((size_t)BATCH * GH * GW)   // 2,484,552 cells

// grid layout: [b][gy][gx][cin], cin contiguous (32B per cell, 32B-aligned)
__device__ __forceinline__ size_t cell_idx(int b, int gy, int gx) {
    return ((size_t)b * GH + gy) * GW + gx;
}

__device__ __forceinline__ void point_cell(const float4 q, int point,
                                           int& b, int& gy, int& gx) {
    gy = (int)rintf(q.z * (float)HEIGHT) + 1;   // padded coord
    gx = (int)rintf(q.y * (float)WIDTH) + 1;
    b  = point >> 14;                           // NPTS = 16384
}

// Pass A: one u32 atomic per point onto the per-cell counter.
__global__ void count_kernel(const float4* __restrict__ xytp,
                             unsigned int* __restrict__ cnt) {
    int point = blockIdx.x * blockDim.x + threadIdx.x;
    if (point >= NPTOT) return;
    float4 q = xytp[point];
    int b, gy, gx;
    point_cell(q, point, b, gy, gx);
    atomicAdd(&cnt[cell_idx(b, gy, gx)], 1u);
}

// Pass B: count==1 (~96%) -> plain 32B store; count>=2 -> 8 f32 HW atomics.
__global__ void write_kernel(const float4* __restrict__ xytp,
                             const float*  __restrict__ feats,
                             const unsigned int* __restrict__ cnt,
                             float* __restrict__ grid) {
    int point = blockIdx.x * blockDim.x + threadIdx.x;
    if (point >= NPTOT) return;
    float4 q = xytp[point];
    int b, gy, gx;
    point_cell(q, point, b, gy, gx);
    size_t ci = cell_idx(b, gy, gx);

    const float* f = feats + (size_t)point * IN_CH;
    float v0 = q.w, v1 = 1.0f - q.w;
    float f0 = f[0], f1 = f[1], f2 = f[2], f3 = f[3], f4 = f[4], f5 = f[5];

    float* cell = grid + (ci << 3);
    if (cnt[ci] == 1u) {
        *(float4*)(cell)     = make_float4(v0, v1, f0, f1);
        *(float4*)(cell + 4) = make_float4(f2, f3, f4, f5);
    } else {
        unsafeAtomicAdd(cell + 0, v0);
        unsafeAtomicAdd(cell + 1, v1);
        unsafeAtomicAdd(cell + 2, f0);
        unsafeAtomicAdd(cell + 3, f1);
        unsafeAtomicAdd(cell + 4, f2);
        unsafeAtomicAdd(cell + 5, f3);
        unsafeAtomicAdd(cell + 6, f4);
        unsafeAtomicAdd(cell + 7, f5);
    }
}

// Legacy single-pass scatter (fallback if ws too small for counters).
__global__ void scatter_kernel(const float4* __restrict__ xytp,
                               const float*  __restrict__ feats,
                               float* __restrict__ grid) {
    int idx = blockIdx.x * blockDim.x + threadIdx.x;
    if (idx >= NPTOT * CIN) return;
    int c     = idx >> 17;
    int point = idx & (NPTOT - 1);
    float4 q = xytp[point];
    int b, gy, gx;
    point_cell(q, point, b, gy, gx);
    float v;
    if (c == 0)      v = q.w;
    else if (c == 1) v = 1.0f - q.w;
    else             v = feats[(size_t)point * IN_CH + (c - 2)];
    unsafeAtomicAdd(grid + (cell_idx(b, gy, gx) << 3) + c, v);
}

// One thread per point, all 32 output channels.
__global__ void conv_gather_kernel(const float4* __restrict__ xytp,
                                   const float*  __restrict__ grid,
                                   const float*  __restrict__ W,     // [3][3][8][32]
                                   const float*  __restrict__ bias,  // [32]
                                   float* __restrict__ out) {
    int idx = blockIdx.x * blockDim.x + threadIdx.x;
    if (idx >= NPTOT) return;
    float4 q = xytp[idx];
    int gy = (int)rintf(q.z * (float)HEIGHT);   // window = padded rows gy..gy+2
    int gx = (int)rintf(q.y * (float)WIDTH);
    int b  = idx >> 14;

    float acc[COUT];
#pragma unroll
    for (int c = 0; c < COUT; ++c) acc[c] = bias[c];

    const float* gbase = grid + (cell_idx(b, gy, gx) << 3);

#pragma unroll
    for (int ky = 0; ky < 3; ++ky) {
#pragma unroll
        for (int kx = 0; kx < 3; ++kx) {
            const float* cell = gbase + ((size_t)(ky * GW + kx) << 3);
            float4 g0 = *(const float4*)(cell);
            float4 g1 = *(const float4*)(cell + 4);
            float g[CIN] = {g0.x, g0.y, g0.z, g0.w, g1.x, g1.y, g1.z, g1.w};
            const float* wp = W + (ky * 3 + kx) * CIN * COUT;
#pragma unroll
            for (int ci = 0; ci < CIN; ++ci) {
#pragma unroll
                for (int c = 0; c < COUT; ++c) {
                    acc[c] = fmaf(g[ci], wp[ci * COUT + c], acc[c]);
                }
            }
        }
    }

    float* o = out + (size_t)idx * COUT;
#pragma unroll
    for (int c = 0; c < COUT; c += 4) {
        *(float4*)(o + c) = make_float4(acc[c], acc[c + 1], acc[c + 2], acc[c + 3]);
    }
}

extern "C" void kernel_launch(void* const* d_in, const int* in_sizes, int n_in,
                              void* d_out, int out_size, void* d_ws, size_t ws_size,
                              hipStream_t stream) {
    const float4* xytp  = (const float4*)d_in[0];   // (8,16384,4)
    const float*  feats = (const float*)d_in[1];    // (8,16384,6)
    const float*  W     = (const float*)d_in[2];    // (3,3,8,32)
    const float*  bias  = (const float*)d_in[3];    // (32,)
    float* out = (float*)d_out;                     // (8,16384,32)

    float* grid = (float*)d_ws;
    const size_t grid_bytes = NCELLS * CIN * sizeof(float);      // ~79.5 MB
    const size_t cnt_bytes  = NCELLS * sizeof(unsigned int);     // ~9.9 MB
    unsigned int* cnt = (unsigned int*)((char*)d_ws + grid_bytes);

    const int blk = 256;
    const int nblk_pts = (NPTOT + blk - 1) / blk;

    if (ws_size >= grid_bytes + cnt_bytes) {
        // zero grid + counters in one memset
        hipMemsetAsync(d_ws, 0, grid_bytes + cnt_bytes, stream);
        count_kernel<<<nblk_pts, blk, 0, stream>>>(xytp, cnt);
        write_kernel<<<nblk_pts, blk, 0, stream>>>(xytp, feats, cnt, grid);
    } else {
        // fallback: single-pass atomic scatter
        hipMemsetAsync(d_ws, 0, grid_bytes, stream);
        const int n_scatter = NPTOT * CIN;
        scatter_kernel<<<(n_scatter + blk - 1) / blk, blk, 0, stream>>>(xytp, feats, grid);
    }

    conv_gather_kernel<<<nblk_pts, blk, 0, stream>>>(xytp, grid, W, bias, out);
}

// Round 5
// 56.364 us; speedup vs baseline: 2.1279x; 1.1490x over previous
//
#include <hip/hip_runtime.h>
#include <hip/hip_bf16.h>

// Problem constants
#define HEIGHT 480
#define WIDTH  640
#define IN_CH  6
#define CIN    8      // p, 1-p, 6 features
#define COUT   32
#define BATCH  8
#define NPTS   16384
#define NPTOT  (BATCH * NPTS)          // 131072 = 2^17
// Padded grid: rows 0..482 (point rows 1..481), cols 0..642 (point cols 1..641)
#define GH 483
#define GW 643
#define NCELLS ((size_t)BATCH * GH * GW)   // 2,484,552 cells (divisible by 4)

// grid layout: [b][gy][gx][cin], cin contiguous (32B per cell, 32B-aligned)
__device__ __forceinline__ size_t cell_idx(int b, int gy, int gx) {
    return ((size_t)b * GH + gy) * GW + gx;
}

__device__ __forceinline__ void point_cell(const float4 q, int point,
                                           int& b, int& gy, int& gx) {
    gy = (int)rintf(q.z * (float)HEIGHT) + 1;   // padded coord
    gx = (int)rintf(q.y * (float)WIDTH) + 1;
    b  = point >> 14;                           // NPTS = 16384
}

// Pass A: one u32 atomic per point onto the per-cell counter.
__global__ void count_kernel(const float4* __restrict__ xytp,
                             unsigned int* __restrict__ cnt) {
    int point = blockIdx.x * blockDim.x + threadIdx.x;
    if (point >= NPTOT) return;
    float4 q = xytp[point];
    int b, gy, gx;
    point_cell(q, point, b, gy, gx);
    atomicAdd(&cnt[cell_idx(b, gy, gx)], 1u);
}

// Pass A.5: zero only the grid cells that will be accumulated into (cnt>=2).
// Coalesced uint4 sweep of cnt; ~4K scattered 32B zero-stores.
__global__ void prep_kernel(const unsigned int* __restrict__ cnt,
                            float* __restrict__ grid) {
    size_t i = (size_t)(blockIdx.x * blockDim.x + threadIdx.x) * 4;
    if (i >= NCELLS) return;
    uint4 c4 = *(const uint4*)(cnt + i);
    const float4 z = make_float4(0.f, 0.f, 0.f, 0.f);
#pragma unroll
    for (int k = 0; k < 4; ++k) {
        unsigned int c = (k == 0) ? c4.x : (k == 1) ? c4.y : (k == 2) ? c4.z : c4.w;
        if (c >= 2u) {
            float* cell = grid + ((i + k) << 3);
            *(float4*)(cell)     = z;
            *(float4*)(cell + 4) = z;
        }
    }
}

// Pass B: count==1 (~96%) -> plain 32B store (overwrites stale data);
//         count>=2 -> 8 f32 HW atomics into the zeroed cell.
__global__ void write_kernel(const float4* __restrict__ xytp,
                             const float*  __restrict__ feats,
                             const unsigned int* __restrict__ cnt,
                             float* __restrict__ grid) {
    int point = blockIdx.x * blockDim.x + threadIdx.x;
    if (point >= NPTOT) return;
    float4 q = xytp[point];
    int b, gy, gx;
    point_cell(q, point, b, gy, gx);
    size_t ci = cell_idx(b, gy, gx);

    const float* f = feats + (size_t)point * IN_CH;
    float v0 = q.w, v1 = 1.0f - q.w;
    float f0 = f[0], f1 = f[1], f2 = f[2], f3 = f[3], f4 = f[4], f5 = f[5];

    float* cell = grid + (ci << 3);
    if (cnt[ci] == 1u) {
        *(float4*)(cell)     = make_float4(v0, v1, f0, f1);
        *(float4*)(cell + 4) = make_float4(f2, f3, f4, f5);
    } else {
        unsafeAtomicAdd(cell + 0, v0);
        unsafeAtomicAdd(cell + 1, v1);
        unsafeAtomicAdd(cell + 2, f0);
        unsafeAtomicAdd(cell + 3, f1);
        unsafeAtomicAdd(cell + 4, f2);
        unsafeAtomicAdd(cell + 5, f3);
        unsafeAtomicAdd(cell + 6, f4);
        unsafeAtomicAdd(cell + 7, f5);
    }
}

// One thread per point, all 32 output channels. Skips empty cells via cnt
// (required: empty cells hold garbage; also cuts gathers ~6x at 5% occupancy).
__global__ void conv_gather_kernel(const float4* __restrict__ xytp,
                                   const float*  __restrict__ grid,
                                   const unsigned int* __restrict__ cnt,
                                   const float*  __restrict__ W,     // [3][3][8][32]
                                   const float*  __restrict__ bias,  // [32]
                                   float* __restrict__ out) {
    int idx = blockIdx.x * blockDim.x + threadIdx.x;
    if (idx >= NPTOT) return;
    float4 q = xytp[idx];
    int gy = (int)rintf(q.z * (float)HEIGHT);   // window = padded rows gy..gy+2
    int gx = (int)rintf(q.y * (float)WIDTH);
    int b  = idx >> 14;

    float acc[COUT];
#pragma unroll
    for (int c = 0; c < COUT; ++c) acc[c] = bias[c];

    size_t base_ci = cell_idx(b, gy, gx);   // top-left of padded 3x3 window

#pragma unroll
    for (int ky = 0; ky < 3; ++ky) {
#pragma unroll
        for (int kx = 0; kx < 3; ++kx) {
            size_t ci = base_ci + (size_t)(ky * GW + kx);
            if (cnt[ci] != 0u) {
                const float* cell = grid + (ci << 3);
                float4 g0 = *(const float4*)(cell);
                float4 g1 = *(const float4*)(cell + 4);
                float g[CIN] = {g0.x, g0.y, g0.z, g0.w, g1.x, g1.y, g1.z, g1.w};
                const float* wp = W + (ky * 3 + kx) * CIN * COUT;
#pragma unroll
                for (int ci2 = 0; ci2 < CIN; ++ci2) {
#pragma unroll
                    for (int c = 0; c < COUT; ++c) {
                        acc[c] = fmaf(g[ci2], wp[ci2 * COUT + c], acc[c]);
                    }
                }
            }
        }
    }

    float* o = out + (size_t)idx * COUT;
#pragma unroll
    for (int c = 0; c < COUT; c += 4) {
        *(float4*)(o + c) = make_float4(acc[c], acc[c + 1], acc[c + 2], acc[c + 3]);
    }
}

extern "C" void kernel_launch(void* const* d_in, const int* in_sizes, int n_in,
                              void* d_out, int out_size, void* d_ws, size_t ws_size,
                              hipStream_t stream) {
    const float4* xytp  = (const float4*)d_in[0];   // (8,16384,4)
    const float*  feats = (const float*)d_in[1];    // (8,16384,6)
    const float*  W     = (const float*)d_in[2];    // (3,3,8,32)
    const float*  bias  = (const float*)d_in[3];    // (32,)
    float* out = (float*)d_out;                     // (8,16384,32)

    float* grid = (float*)d_ws;
    const size_t grid_bytes = NCELLS * CIN * sizeof(float);      // ~79.5 MB
    unsigned int* cnt = (unsigned int*)((char*)d_ws + grid_bytes);
    const size_t cnt_bytes = NCELLS * sizeof(unsigned int);      // ~9.9 MB
    (void)ws_size; (void)cnt_bytes;

    const int blk = 256;
    const int nblk_pts = (NPTOT + blk - 1) / blk;

    // Zero ONLY the counters (grid cells are overwritten or prep-zeroed).
    hipMemsetAsync(cnt, 0, cnt_bytes, stream);

    count_kernel<<<nblk_pts, blk, 0, stream>>>(xytp, cnt);

    const size_t n_prep = NCELLS / 4;
    prep_kernel<<<(int)((n_prep + blk - 1) / blk), blk, 0, stream>>>(cnt, grid);

    write_kernel<<<nblk_pts, blk, 0, stream>>>(xytp, feats, cnt, grid);

    conv_gather_kernel<<<nblk_pts, blk, 0, stream>>>(xytp, grid, cnt, W, bias, out);
}

// Round 6
// 55.728 us; speedup vs baseline: 2.1522x; 1.0114x over previous
//
#include <hip/hip_runtime.h>
#include <hip/hip_bf16.h>

// Problem constants
#define HEIGHT 480
#define WIDTH  640
#define IN_CH  6
#define CIN    8      // p, 1-p, 6 features
#define COUT   32
#define BATCH  8
#define NPTS   16384
#define NPTOT  (BATCH * NPTS)          // 131072 = 2^17
// Padded grid: rows 0..482 (point rows 1..481), cols 0..642 (point cols 1..641)
#define GH 483
#define GW 643
#define NCELLS ((size_t)BATCH * GH * GW)   // 2,484,552 cells (divisible by 4)

// grid layout: [b][gy][gx][cin], cin contiguous (32B per cell, 32B-aligned)
__device__ __forceinline__ size_t cell_idx(int b, int gy, int gx) {
    return ((size_t)b * GH + gy) * GW + gx;
}

__device__ __forceinline__ void point_cell(const float4 q, int point,
                                           int& b, int& gy, int& gx) {
    gy = (int)rintf(q.z * (float)HEIGHT) + 1;   // padded coord
    gx = (int)rintf(q.y * (float)WIDTH) + 1;
    b  = point >> 14;                           // NPTS = 16384
}

// Custom zero-fill for the counter array (runtime fillBufferAligned has a
// ~40us floor in the graph-captured path; this is a plain 9.9MB write ~2us).
__global__ void zero_cnt_kernel(uint4* __restrict__ cnt4) {
    size_t i = (size_t)blockIdx.x * blockDim.x + threadIdx.x;
    if (i < NCELLS / 4) cnt4[i] = make_uint4(0u, 0u, 0u, 0u);
}

// Pass A: one u32 atomic per point onto the per-cell counter.
__global__ void count_kernel(const float4* __restrict__ xytp,
                             unsigned int* __restrict__ cnt) {
    int point = blockIdx.x * blockDim.x + threadIdx.x;
    if (point >= NPTOT) return;
    float4 q = xytp[point];
    int b, gy, gx;
    point_cell(q, point, b, gy, gx);
    atomicAdd(&cnt[cell_idx(b, gy, gx)], 1u);
}

// Pass A.5: zero only the grid cells that will be accumulated into (cnt>=2).
// Coalesced uint4 sweep of cnt; ~4K scattered 32B zero-stores.
__global__ void prep_kernel(const unsigned int* __restrict__ cnt,
                            float* __restrict__ grid) {
    size_t i = (size_t)(blockIdx.x * blockDim.x + threadIdx.x) * 4;
    if (i >= NCELLS) return;
    uint4 c4 = *(const uint4*)(cnt + i);
    const float4 z = make_float4(0.f, 0.f, 0.f, 0.f);
#pragma unroll
    for (int k = 0; k < 4; ++k) {
        unsigned int c = (k == 0) ? c4.x : (k == 1) ? c4.y : (k == 2) ? c4.z : c4.w;
        if (c >= 2u) {
            float* cell = grid + ((i + k) << 3);
            *(float4*)(cell)     = z;
            *(float4*)(cell + 4) = z;
        }
    }
}

// Pass B: count==1 (~96%) -> plain 32B store (overwrites stale data);
//         count>=2 -> 8 f32 HW atomics into the zeroed cell.
__global__ void write_kernel(const float4* __restrict__ xytp,
                             const float*  __restrict__ feats,
                             const unsigned int* __restrict__ cnt,
                             float* __restrict__ grid) {
    int point = blockIdx.x * blockDim.x + threadIdx.x;
    if (point >= NPTOT) return;
    float4 q = xytp[point];
    int b, gy, gx;
    point_cell(q, point, b, gy, gx);
    size_t ci = cell_idx(b, gy, gx);

    const float* f = feats + (size_t)point * IN_CH;
    float v0 = q.w, v1 = 1.0f - q.w;
    float f0 = f[0], f1 = f[1], f2 = f[2], f3 = f[3], f4 = f[4], f5 = f[5];

    float* cell = grid + (ci << 3);
    if (cnt[ci] == 1u) {
        *(float4*)(cell)     = make_float4(v0, v1, f0, f1);
        *(float4*)(cell + 4) = make_float4(f2, f3, f4, f5);
    } else {
        unsafeAtomicAdd(cell + 0, v0);
        unsafeAtomicAdd(cell + 1, v1);
        unsafeAtomicAdd(cell + 2, f0);
        unsafeAtomicAdd(cell + 3, f1);
        unsafeAtomicAdd(cell + 4, f2);
        unsafeAtomicAdd(cell + 5, f3);
        unsafeAtomicAdd(cell + 6, f4);
        unsafeAtomicAdd(cell + 7, f5);
    }
}

// One thread per point, all 32 output channels. Skips empty cells via cnt
// (required: empty cells hold garbage; also cuts gathers ~6x at 5% occupancy).
__global__ void conv_gather_kernel(const float4* __restrict__ xytp,
                                   const float*  __restrict__ grid,
                                   const unsigned int* __restrict__ cnt,
                                   const float*  __restrict__ W,     // [3][3][8][32]
                                   const float*  __restrict__ bias,  // [32]
                                   float* __restrict__ out) {
    int idx = blockIdx.x * blockDim.x + threadIdx.x;
    if (idx >= NPTOT) return;
    float4 q = xytp[idx];
    int gy = (int)rintf(q.z * (float)HEIGHT);   // window = padded rows gy..gy+2
    int gx = (int)rintf(q.y * (float)WIDTH);
    int b  = idx >> 14;

    float acc[COUT];
#pragma unroll
    for (int c = 0; c < COUT; ++c) acc[c] = bias[c];

    size_t base_ci = cell_idx(b, gy, gx);   // top-left of padded 3x3 window

#pragma unroll
    for (int ky = 0; ky < 3; ++ky) {
#pragma unroll
        for (int kx = 0; kx < 3; ++kx) {
            size_t ci = base_ci + (size_t)(ky * GW + kx);
            if (cnt[ci] != 0u) {
                const float* cell = grid + (ci << 3);
                float4 g0 = *(const float4*)(cell);
                float4 g1 = *(const float4*)(cell + 4);
                float g[CIN] = {g0.x, g0.y, g0.z, g0.w, g1.x, g1.y, g1.z, g1.w};
                const float* wp = W + (ky * 3 + kx) * CIN * COUT;
#pragma unroll
                for (int ci2 = 0; ci2 < CIN; ++ci2) {
#pragma unroll
                    for (int c = 0; c < COUT; ++c) {
                        acc[c] = fmaf(g[ci2], wp[ci2 * COUT + c], acc[c]);
                    }
                }
            }
        }
    }

    float* o = out + (size_t)idx * COUT;
#pragma unroll
    for (int c = 0; c < COUT; c += 4) {
        *(float4*)(o + c) = make_float4(acc[c], acc[c + 1], acc[c + 2], acc[c + 3]);
    }
}

extern "C" void kernel_launch(void* const* d_in, const int* in_sizes, int n_in,
                              void* d_out, int out_size, void* d_ws, size_t ws_size,
                              hipStream_t stream) {
    const float4* xytp  = (const float4*)d_in[0];   // (8,16384,4)
    const float*  feats = (const float*)d_in[1];    // (8,16384,6)
    const float*  W     = (const float*)d_in[2];    // (3,3,8,32)
    const float*  bias  = (const float*)d_in[3];    // (32,)
    float* out = (float*)d_out;                     // (8,16384,32)

    float* grid = (float*)d_ws;
    const size_t grid_bytes = NCELLS * CIN * sizeof(float);      // ~79.5 MB
    unsigned int* cnt = (unsigned int*)((char*)d_ws + grid_bytes);
    (void)ws_size;

    const int blk = 256;
    const int nblk_pts = (NPTOT + blk - 1) / blk;

    // Zero ONLY the counters, with our own fill kernel (not hipMemsetAsync).
    const size_t n_fill = NCELLS / 4;                            // 621,138 uint4
    zero_cnt_kernel<<<(int)((n_fill + blk - 1) / blk), blk, 0, stream>>>((uint4*)cnt);

    count_kernel<<<nblk_pts, blk, 0, stream>>>(xytp, cnt);

    const size_t n_prep = NCELLS / 4;
    prep_kernel<<<(int)((n_prep + blk - 1) / blk), blk, 0, stream>>>(cnt, grid);

    write_kernel<<<nblk_pts, blk, 0, stream>>>(xytp, feats, cnt, grid);

    conv_gather_kernel<<<nblk_pts, blk, 0, stream>>>(xytp, grid, cnt, W, bias, out);
}